// Round 4
// baseline (277.744 us; speedup 1.0000x reference)
//
#include <hip/hip_runtime.h>

#define HDIM 4096
#define NIN 17
#define NA 4

using f4 = __attribute__((ext_vector_type(4))) float;

// ---- kernel 1 config: column-ownership matvec + h ----
constexpr int TB1 = 1024;                     // 16 waves/block
constexpr int CPB = 16;                       // columns per block (64B row segment)
constexpr int NBLK1 = HDIM / CPB;             // 256 blocks = 1 per CU
constexpr int RPP = TB1 / 4;                  // 256 rows per pass (4 threads/row)
constexpr int NPASS = HDIM / RPP;             // 16 passes
constexpr size_t NELEM = (size_t)HDIM * HDIM;

// Kernel 1: each block owns 16 columns of the H x H matrices.
//   h[j] = tanh( i2h(x)[j] + sum_i hidden[i] * (w[i,j] + alpha[i,j]*hebb[i,j]) )
// Thread t: quad q = t&3 (4 cols), row-in-pass = t>>2. Per wave-instr: 16 rows
// x 64B contiguous segments -> full sector efficiency. NORMAL loads (w/alpha/
// hebb re-read every iteration -> let L3 retain all 192 MB).
// No partial tensor, no second reduce kernel.
__global__ __launch_bounds__(TB1)
void k_mvh(const float* __restrict__ w, const float* __restrict__ alpha,
           const float* __restrict__ hebb, const float* __restrict__ hidden,
           const float* __restrict__ x, const float* __restrict__ i2h_w,
           const float* __restrict__ i2h_b,
           const float* __restrict__ h2o_w, const float* __restrict__ h2v_w,
           float* __restrict__ h_f, float* __restrict__ out,
           float* __restrict__ acc5) {
    const int tid = threadIdx.x;
    const int q = tid & 3;                    // which float4 of the 16-col slab
    const int rw = tid >> 2;                  // row within pass (0..255)
    const int colq = blockIdx.x * CPB + q * 4;

    f4 acc = {0.f, 0.f, 0.f, 0.f};
#pragma unroll 4
    for (int p = 0; p < NPASS; ++p) {
        const int r = p * RPP + rw;
        const size_t off = (size_t)r * HDIM + colq;
        const f4 wv = *(const f4*)(w + off);
        const f4 av = *(const f4*)(alpha + off);
        const f4 bv = *(const f4*)(hebb + off);
        acc += hidden[r] * (wv + av * bv);
    }

    __shared__ f4 red[TB1];                   // 16 KB
    red[tid] = acc;
    __syncthreads();
    // strides are multiples of 4 -> stays within the same col-quad
    for (int s = TB1 / 2; s >= 4; s >>= 1) {
        if (tid < s) red[tid] += red[tid + s];
        __syncthreads();
    }

    __shared__ float hsh[CPB];
    if (tid < CPB) {
        const int j = blockIdx.x * CPB + tid;
        float z = red[tid >> 2][tid & 3] + i2h_b[j];
#pragma unroll
        for (int k = 0; k < NIN; ++k) z += x[k] * i2h_w[j * NIN + k];
        const float h = tanhf(z);
        h_f[j] = h;
        out[5 + j] = h;
        hsh[tid] = h;
    }
    __syncthreads();

    // head-dot contributions for this block's 16 columns
    if (tid == 0) {
        float a5[NA + 1] = {0.f, 0.f, 0.f, 0.f, 0.f};
#pragma unroll
        for (int c = 0; c < CPB; ++c) {
            const int j = blockIdx.x * CPB + c;
            const float h = hsh[c];
#pragma unroll
            for (int a = 0; a < NA; ++a) a5[a] += h * h2o_w[(size_t)a * HDIM + j];
            a5[NA] += h * h2v_w[j];
        }
#pragma unroll
        for (int a = 0; a <= NA; ++a) atomicAdd(acc5 + a, a5[a]);
    }
}

// Kernel 2: hebb_new = (1-eta)*hebb + eta*outer(hidden, h).
// s = 4t+3 alignment trick (out+4101 base) -> aligned float4 NT stores
// (write-once stream: don't evict the L3-resident inputs).
constexpr int TB2 = 256;

__global__ __launch_bounds__(TB2)
void k_hebb(const float* __restrict__ hebb, const float* __restrict__ hidden,
            const float* __restrict__ h_f, const float* __restrict__ eta,
            float* __restrict__ hebb_out) {
    const size_t t = (size_t)blockIdx.x * TB2 + threadIdx.x;
    const size_t s = 4 * t + 3;
    const float e = eta[0];
    const float om = 1.f - e;

    if (t == 0) {  // head elements 0,1,2 (row 0)
        const float hv0 = e * hidden[0];
        hebb_out[0] = om * hebb[0] + hv0 * h_f[0];
        hebb_out[1] = om * hebb[1] + hv0 * h_f[1];
        hebb_out[2] = om * hebb[2] + hv0 * h_f[2];
    }

    if (s + 3 < NELEM) {
        const float b0 = hebb[s];                        // 4B-aligned scalar
        const f4 bv = *(const f4*)(hebb + s + 1);        // 16B-aligned
        const float b[4] = {b0, bv.x, bv.y, bv.z};
        f4 v;
#pragma unroll
        for (int k = 0; k < 4; ++k) {
            const size_t m = s + (size_t)k;
            const int i = (int)(m >> 12);
            const int jj = (int)(m & (HDIM - 1));
            v[k] = om * b[k] + e * hidden[i] * h_f[jj];
        }
        __builtin_nontemporal_store(v, (f4*)(hebb_out + s));  // 16B-aligned
    } else {
        for (size_t m = s; m < NELEM; ++m) {             // tail element N-1
            const int i = (int)(m >> 12);
            const int jj = (int)(m & (HDIM - 1));
            hebb_out[m] = om * hebb[m] + e * hidden[i] * h_f[jj];
        }
    }
}

// Kernel 3: tiny finalize — softmax + value head.
__global__ __launch_bounds__(64)
void k_finish(const float* __restrict__ acc5,
              const float* __restrict__ h2o_b, const float* __restrict__ h2v_b,
              float* __restrict__ out) {
    if (threadIdx.x == 0) {
        float o[NA];
        float mx = -1e30f;
#pragma unroll
        for (int a = 0; a < NA; ++a) { o[a] = acc5[a] + h2o_b[a]; mx = fmaxf(mx, o[a]); }
        float se = 0.f;
#pragma unroll
        for (int a = 0; a < NA; ++a) { o[a] = __expf(o[a] - mx); se += o[a]; }
#pragma unroll
        for (int a = 0; a < NA; ++a) out[a] = o[a] / se;
        out[NA] = acc5[NA] + h2v_b[0];
    }
}

extern "C" void kernel_launch(void* const* d_in, const int* in_sizes, int n_in,
                              void* d_out, int out_size, void* d_ws, size_t ws_size,
                              hipStream_t stream) {
    const float* x      = (const float*)d_in[0];
    const float* hidden = (const float*)d_in[1];
    const float* hebb   = (const float*)d_in[2];
    const float* i2h_w  = (const float*)d_in[3];
    const float* i2h_b  = (const float*)d_in[4];
    const float* w      = (const float*)d_in[5];
    const float* alpha  = (const float*)d_in[6];
    const float* eta    = (const float*)d_in[7];
    const float* h2o_w  = (const float*)d_in[8];
    const float* h2o_b  = (const float*)d_in[9];
    const float* h2v_w  = (const float*)d_in[10];
    const float* h2v_b  = (const float*)d_in[11];
    float* out = (float*)d_out;

    // out layout: activout[4] | valueout[1] | h[4096] | hebb_new[4096*4096]
    float* hebb_out = out + 5 + HDIM;

    float* h_f  = (float*)d_ws;        // HDIM floats
    float* acc5 = h_f + HDIM;          // 8 floats (5 used)

    hipMemsetAsync(acc5, 0, 8 * sizeof(float), stream);
    k_mvh<<<NBLK1, TB1, 0, stream>>>(w, alpha, hebb, hidden, x, i2h_w, i2h_b,
                                     h2o_w, h2v_w, h_f, out, acc5);
    k_hebb<<<(int)((NELEM / 4) / TB2), TB2, 0, stream>>>(hebb, hidden, h_f, eta, hebb_out);
    k_finish<<<1, 64, 0, stream>>>(acc5, h2o_b, h2v_b, out);
}

// Round 5
// 273.800 us; speedup vs baseline: 1.0144x; 1.0144x over previous
//
#include <hip/hip_runtime.h>
#include <hip/hip_cooperative_groups.h>

namespace cg = cooperative_groups;

#define HDIM 4096
#define NIN 17
#define NA 4

using f4 = __attribute__((ext_vector_type(4))) float;

// ---- config ----
constexpr int TB1 = 1024;                     // 16 waves/block
constexpr int CPB = 16;                       // columns per block (64B row segment)
constexpr int NBLK1 = HDIM / CPB;             // 256 blocks = 1 per CU
constexpr int RPP = TB1 / 4;                  // 256 rows per pass (4 threads/row)
constexpr int NPASS = HDIM / RPP;             // 16 passes
constexpr size_t NELEM = (size_t)HDIM * HDIM;
constexpr size_t NQUAD = NELEM / 4;           // 4M quads for phase 3

// ============================================================================
// Single fused cooperative kernel (R2 structure, R4 phase quality).
// 256 blocks x 1024 threads = exactly 1 block/CU, co-resident.
//
// Phase 1 (per block, independent): column-slab matvec over 16 columns
//   -> h[j] = tanh(i2h + matvec) for its 16 cols; head-dot atomics.
// grid.sync()
// Phase 2 (block 0): softmax + value finalize.
// Phase 3 (all blocks): hebb_new = (1-eta)*hebb + eta*outer(hidden,h),
//   grid-strided, 4t+3-aligned float4 NT stores (out+4101 base).
//   hebb re-read is L3-hot (streamed moments ago in phase 1).
// ============================================================================
__global__ __launch_bounds__(TB1)
void k_all(const float* __restrict__ w, const float* __restrict__ alpha,
           const float* __restrict__ hebb, const float* __restrict__ hidden,
           const float* __restrict__ x, const float* __restrict__ i2h_w,
           const float* __restrict__ i2h_b,
           const float* __restrict__ h2o_w, const float* __restrict__ h2o_b,
           const float* __restrict__ h2v_w, const float* __restrict__ h2v_b,
           const float* __restrict__ eta,
           float* __restrict__ h_f, float* __restrict__ out,
           float* __restrict__ acc5) {
    const int tid = threadIdx.x;
    const int q = tid & 3;                    // which float4 of the 16-col slab
    const int rw = tid >> 2;                  // row within pass (0..255)
    const int colq = blockIdx.x * CPB + q * 4;

    // ---------------- phase 1: column-slab matvec + h + head dots -----------
    f4 acc = {0.f, 0.f, 0.f, 0.f};
#pragma unroll 4
    for (int p = 0; p < NPASS; ++p) {
        const int r = p * RPP + rw;
        const size_t off = (size_t)r * HDIM + colq;
        const f4 wv = *(const f4*)(w + off);
        const f4 av = *(const f4*)(alpha + off);
        const f4 bv = *(const f4*)(hebb + off);
        acc += hidden[r] * (wv + av * bv);
    }

    __shared__ f4 red[TB1];                   // 16 KB
    red[tid] = acc;
    __syncthreads();
    for (int s = TB1 / 2; s >= 4; s >>= 1) {  // strides stay within col-quad
        if (tid < s) red[tid] += red[tid + s];
        __syncthreads();
    }

    if (tid < CPB) {
        const int j = blockIdx.x * CPB + tid;
        float z = red[tid >> 2][tid & 3] + i2h_b[j];
#pragma unroll
        for (int k = 0; k < NIN; ++k) z += x[k] * i2h_w[j * NIN + k];
        const float h = tanhf(z);
        h_f[j] = h;
        out[5 + j] = h;
        // head-dot partials: tid 0..15 are lanes 0..15 of wave 0
        float d[NA + 1];
#pragma unroll
        for (int a = 0; a < NA; ++a) d[a] = h * h2o_w[(size_t)a * HDIM + j];
        d[NA] = h * h2v_w[j];
#pragma unroll
        for (int a = 0; a <= NA; ++a) {
            float v = d[a];
#pragma unroll
            for (int sft = 8; sft > 0; sft >>= 1) v += __shfl_down(v, sft, 16);
            if (tid == 0) atomicAdd(acc5 + a, v);
        }
    }

    cg::this_grid().sync();

    // ---------------- phase 2: softmax + value finalize (block 0) -----------
    if (blockIdx.x == 0 && tid == 0) {
        float o[NA];
        float mx = -1e30f;
#pragma unroll
        for (int a = 0; a < NA; ++a) { o[a] = acc5[a] + h2o_b[a]; mx = fmaxf(mx, o[a]); }
        float se = 0.f;
#pragma unroll
        for (int a = 0; a < NA; ++a) { o[a] = __expf(o[a] - mx); se += o[a]; }
#pragma unroll
        for (int a = 0; a < NA; ++a) out[a] = o[a] / se;
        out[NA] = acc5[NA] + h2v_b[0];
    }

    // ---------------- phase 3: hebb update, grid-strided, aligned NT stores -
    float* __restrict__ hebb_out = out + 5 + HDIM;   // element offset 4101
    const float e = eta[0];
    const float om = 1.f - e;
    const size_t G = (size_t)NBLK1 * TB1;            // 262144 threads
    const size_t tg = (size_t)blockIdx.x * TB1 + tid;

    if (tg == 0) {  // head elements 0,1,2 (row 0)
        const float hv0 = e * hidden[0];
        hebb_out[0] = om * hebb[0] + hv0 * h_f[0];
        hebb_out[1] = om * hebb[1] + hv0 * h_f[1];
        hebb_out[2] = om * hebb[2] + hv0 * h_f[2];
    }

    for (size_t k = tg; k < NQUAD; k += G) {
        const size_t s = 4 * k + 3;
        if (s + 3 < NELEM) {
            const float b0 = hebb[s];                    // 4B-aligned scalar
            const f4 bv = *(const f4*)(hebb + s + 1);    // 16B-aligned
            const float b[4] = {b0, bv.x, bv.y, bv.z};
            f4 v;
#pragma unroll
            for (int kk = 0; kk < 4; ++kk) {
                const size_t m = s + (size_t)kk;
                const int i = (int)(m >> 12);
                const int jj = (int)(m & (HDIM - 1));
                v[kk] = om * b[kk] + e * hidden[i] * h_f[jj];
            }
            __builtin_nontemporal_store(v, (f4*)(hebb_out + s));  // 16B-aligned
        } else {
            for (size_t m = s; m < NELEM; ++m) {         // tail element
                const int i = (int)(m >> 12);
                const int jj = (int)(m & (HDIM - 1));
                hebb_out[m] = om * hebb[m] + e * hidden[i] * h_f[jj];
            }
        }
    }
}

// ============================================================================
// Fallback (R4's 3-kernel path) if cooperative co-residency fails.
// ============================================================================
__global__ __launch_bounds__(TB1)
void k_mvh(const float* __restrict__ w, const float* __restrict__ alpha,
           const float* __restrict__ hebb, const float* __restrict__ hidden,
           const float* __restrict__ x, const float* __restrict__ i2h_w,
           const float* __restrict__ i2h_b,
           const float* __restrict__ h2o_w, const float* __restrict__ h2v_w,
           float* __restrict__ h_f, float* __restrict__ out,
           float* __restrict__ acc5) {
    const int tid = threadIdx.x;
    const int q = tid & 3;
    const int rw = tid >> 2;
    const int colq = blockIdx.x * CPB + q * 4;
    f4 acc = {0.f, 0.f, 0.f, 0.f};
#pragma unroll 4
    for (int p = 0; p < NPASS; ++p) {
        const int r = p * RPP + rw;
        const size_t off = (size_t)r * HDIM + colq;
        const f4 wv = *(const f4*)(w + off);
        const f4 av = *(const f4*)(alpha + off);
        const f4 bv = *(const f4*)(hebb + off);
        acc += hidden[r] * (wv + av * bv);
    }
    __shared__ f4 red[TB1];
    red[tid] = acc;
    __syncthreads();
    for (int s = TB1 / 2; s >= 4; s >>= 1) {
        if (tid < s) red[tid] += red[tid + s];
        __syncthreads();
    }
    if (tid < CPB) {
        const int j = blockIdx.x * CPB + tid;
        float z = red[tid >> 2][tid & 3] + i2h_b[j];
#pragma unroll
        for (int k = 0; k < NIN; ++k) z += x[k] * i2h_w[j * NIN + k];
        const float h = tanhf(z);
        h_f[j] = h;
        out[5 + j] = h;
        float d[NA + 1];
#pragma unroll
        for (int a = 0; a < NA; ++a) d[a] = h * h2o_w[(size_t)a * HDIM + j];
        d[NA] = h * h2v_w[j];
#pragma unroll
        for (int a = 0; a <= NA; ++a) {
            float v = d[a];
#pragma unroll
            for (int sft = 8; sft > 0; sft >>= 1) v += __shfl_down(v, sft, 16);
            if (tid == 0) atomicAdd(acc5 + a, v);
        }
    }
}

constexpr int TB2 = 256;

__global__ __launch_bounds__(TB2)
void k_hebb(const float* __restrict__ hebb, const float* __restrict__ hidden,
            const float* __restrict__ h_f, const float* __restrict__ eta,
            float* __restrict__ hebb_out) {
    const size_t t = (size_t)blockIdx.x * TB2 + threadIdx.x;
    const size_t s = 4 * t + 3;
    const float e = eta[0];
    const float om = 1.f - e;
    if (t == 0) {
        const float hv0 = e * hidden[0];
        hebb_out[0] = om * hebb[0] + hv0 * h_f[0];
        hebb_out[1] = om * hebb[1] + hv0 * h_f[1];
        hebb_out[2] = om * hebb[2] + hv0 * h_f[2];
    }
    if (s + 3 < NELEM) {
        const float b0 = hebb[s];
        const f4 bv = *(const f4*)(hebb + s + 1);
        const float b[4] = {b0, bv.x, bv.y, bv.z};
        f4 v;
#pragma unroll
        for (int k = 0; k < 4; ++k) {
            const size_t m = s + (size_t)k;
            const int i = (int)(m >> 12);
            const int jj = (int)(m & (HDIM - 1));
            v[k] = om * b[k] + e * hidden[i] * h_f[jj];
        }
        __builtin_nontemporal_store(v, (f4*)(hebb_out + s));
    } else {
        for (size_t m = s; m < NELEM; ++m) {
            const int i = (int)(m >> 12);
            const int jj = (int)(m & (HDIM - 1));
            hebb_out[m] = om * hebb[m] + e * hidden[i] * h_f[jj];
        }
    }
}

__global__ __launch_bounds__(64)
void k_finish(const float* __restrict__ acc5,
              const float* __restrict__ h2o_b, const float* __restrict__ h2v_b,
              float* __restrict__ out) {
    if (threadIdx.x == 0) {
        float o[NA];
        float mx = -1e30f;
#pragma unroll
        for (int a = 0; a < NA; ++a) { o[a] = acc5[a] + h2o_b[a]; mx = fmaxf(mx, o[a]); }
        float se = 0.f;
#pragma unroll
        for (int a = 0; a < NA; ++a) { o[a] = __expf(o[a] - mx); se += o[a]; }
#pragma unroll
        for (int a = 0; a < NA; ++a) out[a] = o[a] / se;
        out[NA] = acc5[NA] + h2v_b[0];
    }
}

extern "C" void kernel_launch(void* const* d_in, const int* in_sizes, int n_in,
                              void* d_out, int out_size, void* d_ws, size_t ws_size,
                              hipStream_t stream) {
    const float* x      = (const float*)d_in[0];
    const float* hidden = (const float*)d_in[1];
    const float* hebb   = (const float*)d_in[2];
    const float* i2h_w  = (const float*)d_in[3];
    const float* i2h_b  = (const float*)d_in[4];
    const float* w      = (const float*)d_in[5];
    const float* alpha  = (const float*)d_in[6];
    const float* eta    = (const float*)d_in[7];
    const float* h2o_w  = (const float*)d_in[8];
    const float* h2o_b  = (const float*)d_in[9];
    const float* h2v_w  = (const float*)d_in[10];
    const float* h2v_b  = (const float*)d_in[11];
    float* out = (float*)d_out;

    // out layout: activout[4] | valueout[1] | h[4096] | hebb_new[4096*4096]
    float* hebb_out = out + 5 + HDIM;

    float* h_f  = (float*)d_ws;        // HDIM floats
    float* acc5 = h_f + HDIM;          // 8 floats (5 used)

    hipMemsetAsync(acc5, 0, 8 * sizeof(float), stream);

    // Co-residency check: need 256 blocks of 1024 on 256 CUs.
    static int coop = -1;
    if (coop < 0) {
        int maxb = 0;
        hipError_t err = hipOccupancyMaxActiveBlocksPerMultiprocessor(&maxb, k_all, TB1, 0);
        coop = (err == hipSuccess && maxb >= 1) ? 1 : 0;
    }

    if (coop) {
        void* args[] = {(void*)&w, (void*)&alpha, (void*)&hebb, (void*)&hidden,
                        (void*)&x, (void*)&i2h_w, (void*)&i2h_b,
                        (void*)&h2o_w, (void*)&h2o_b, (void*)&h2v_w, (void*)&h2v_b,
                        (void*)&eta, (void*)&h_f, (void*)&out, (void*)&acc5};
        hipLaunchCooperativeKernel(k_all, dim3(NBLK1), dim3(TB1), args, 0, stream);
    } else {
        k_mvh<<<NBLK1, TB1, 0, stream>>>(w, alpha, hebb, hidden, x, i2h_w, i2h_b,
                                         h2o_w, h2v_w, h_f, out, acc5);
        k_hebb<<<(int)(NQUAD / TB2), TB2, 0, stream>>>(hebb, hidden, h_f, eta, hebb_out);
        k_finish<<<1, 64, 0, stream>>>(acc5, h2o_b, h2v_b, out);
    }
}